// Round 5
// baseline (185.659 us; speedup 1.0000x reference)
//
#include <hip/hip_runtime.h>
#include <hip/hip_bf16.h>

typedef __bf16 bf16;
typedef __attribute__((ext_vector_type(8))) __bf16 bf16x8;
typedef __attribute__((ext_vector_type(4))) __bf16 bf16x4;
typedef __attribute__((ext_vector_type(2))) __bf16 bf16x2;
typedef __attribute__((ext_vector_type(4))) float f32x4;

#define C_NODES 63
#define F_DIM   250
#define NEG_SLOPE 0.2f

// LDS layout (32768 B):
//   [0, 32768)     A-fragments of X (GEMM1, swzA-swizzled), then reused as
//                  Hs[f][s] bf16 (f<250, swz-swizzled row-locally).
//   [32000,32256)  AS: a_s[64] f32   (bytes 250*128.. — beyond Hs rows,
//   [32256,32512)  AD: a_d[64] f32    written only after bar1)
#define OFF_AS    32000
#define OFF_AD    32256
#define LDS_BYTES 32768

// Hs swizzle: XOR f&7 into bank bits 4-6; row-local (128B rows).
__device__ __forceinline__ int swz(int a) { return a ^ ((a >> 3) & 0x70); }
// A-frag swizzle: XOR (dl-hi ^ kt-lo) into bits 4-5 and kt-bit2 into bit 6.
// Makes the row-major staging writes bank-uniform; reads stay per-lane
// bijective. Key bits (8-12) unmodified -> bijection, same formula both sides.
__device__ __forceinline__ int swzA(int a) {
    return a ^ ((((a >> 8) & 3) ^ ((a >> 10) & 3)) << 4) ^ (((a >> 12) & 1) << 6);
}

// Pack W (250x250 f32) into bf16 MFMA-B fragment order, padded to 256x256.
// Columns 250/251 hold ws = W@att_src and wd = W@att_dst, so GEMM1 emits the
// per-node scores a_s, a_d directly. Rows k>=250 are zero (kills A-garbage).
extern "C" __global__ __launch_bounds__(256)
void gat_prep(const float* __restrict__ W, const float* __restrict__ att_src,
              const float* __restrict__ att_dst, bf16* __restrict__ Wp) {
    int i = blockIdx.x * 256 + threadIdx.x;   // 0..65535
    int tile = i >> 9;
    int ln   = (i >> 3) & 63;
    int j    = i & 7;
    int kt = tile >> 4, nt = tile & 15;
    int k = kt * 32 + (ln >> 4) * 8 + j;
    int n = nt * 16 + (ln & 15);
    float v = 0.f;
    if (k < F_DIM) {
        if (n < F_DIM) {
            v = W[k * F_DIM + n];
        } else if (n == F_DIM || n == F_DIM + 1) {
            const float* att = (n == F_DIM) ? att_src : att_dst;
            float s = 0.f;
            for (int o = 0; o < F_DIM; ++o) s = fmaf(W[k * F_DIM + o], att[o], s);
            v = s;
        }
    }
    Wp[i] = (bf16)v;
}

extern "C" __global__ __launch_bounds__(256, 4)
void gat_main(const float* __restrict__ x, const bf16* __restrict__ Wp,
              const float* __restrict__ bias, float* __restrict__ out)
{
    __shared__ __align__(16) unsigned char smem[LDS_BYTES];
    const int tid  = threadIdx.x;
    const int lane = tid & 63;
    const int w    = tid >> 6;        // wave id 0..3 -> owns 64 output columns
    const int b    = blockIdx.x;
    const int fl   = lane & 15;
    const int fh   = lane >> 4;

    const bf16x8* wpv = (const bf16x8*)Wp;

    // Wp prefetch for kt=0,1: independent of staging/barrier; issue first so
    // L2 latency hides under the staging phase.
    bf16x8 bwpre0[4], bwpre1[4];
#pragma unroll
    for (int nti = 0; nti < 4; ++nti)
        bwpre0[nti] = wpv[(w * 4 + nti) * 64 + lane];
#pragma unroll
    for (int nti = 0; nti < 4; ++nti)
        bwpre1[nti] = wpv[(16 + w * 4 + nti) * 64 + lane];

    // bias preload (overlaps staging)
    float bv[4];
#pragma unroll
    for (int nti = 0; nti < 4; ++nti) {
        int f = w * 64 + nti * 16 + fl;
        bv[nti] = (f < F_DIM) ? bias[f] : 0.f;
    }

    // NaN-guard: zero the only A-frag slots the scatter never writes.
    if (tid < 64) {
        // c in 250..255 tail: tile (mt,7), dl=48+(r&15), bytes 4..15
        int base = swzA((((tid >> 4) * 8 + 7) << 10) + (48 + (tid & 15)) * 16);
        *(unsigned int*)(smem + base + 4) = 0u;
        *(unsigned long long*)(smem + base + 8) = 0ull;
    } else if (tid < 96) {
        // row r=63: tile (3,kt), dl=((g&3)<<4)|15, full 16 B
        int idx = tid - 64;
        int base = swzA(((24 + (idx >> 2)) << 10) + ((((idx & 3) << 4) | 15) * 16));
        *(f32x4*)(smem + base) = (f32x4){0.f, 0.f, 0.f, 0.f};
    }

    // stage X_b -> bf16 A-fragments (swzA): 63 rows x 32 col-groups,
    // idx = r*32+g; 16B ds_write per full group, bank-conflict-free via swzA.
    {
        const float* xb = x + (size_t)b * (C_NODES * F_DIM);
#pragma unroll
        for (int it = 0; it < 8; ++it) {
            int idx = tid + it * 256;
            if (idx < 2016) {
                int r = idx >> 5, g = idx & 31;
                const float* src = xb + r * F_DIM + g * 8;
                int dl = (r & 15) | ((g & 3) << 4);
                int base = swzA((((r >> 4) * 8 + (g >> 2)) << 10) + dl * 16);
                if (g < 31) {
                    float2 v0 = *(const float2*)(src);
                    float2 v1 = *(const float2*)(src + 2);
                    float2 v2 = *(const float2*)(src + 4);
                    float2 v3 = *(const float2*)(src + 6);
                    bf16x8 pk = { (bf16)v0.x, (bf16)v0.y, (bf16)v1.x, (bf16)v1.y,
                                  (bf16)v2.x, (bf16)v2.y, (bf16)v3.x, (bf16)v3.y };
                    *(bf16x8*)(smem + base) = pk;
                } else {
                    // tail: only c=248,249 valid (j=0,1); j>=2 zeroed by guard
                    float2 v0 = *(const float2*)(src);
                    bf16x2 pk = { (bf16)v0.x, (bf16)v0.y };
                    *(bf16x2*)(smem + base) = pk;
                }
            }
        }
    }
    __syncthreads();   // bar0: A-frags ready

    // ---- GEMM1: H'[64][256] = X @ Wp ; cols 250/251 are a_s/a_d ----
    f32x4 acc[4][4];
#pragma unroll
    for (int mt = 0; mt < 4; ++mt)
#pragma unroll
        for (int nti = 0; nti < 4; ++nti)
            acc[mt][nti] = (f32x4){0.f, 0.f, 0.f, 0.f};
#pragma unroll
    for (int kt = 0; kt < 8; ++kt) {
        bf16x8 af[4], bw[4];
#pragma unroll
        for (int nti = 0; nti < 4; ++nti)
            bw[nti] = (kt == 0) ? bwpre0[nti]
                    : (kt == 1) ? bwpre1[nti]
                    : wpv[(kt * 16 + (w * 4 + nti)) * 64 + lane];
#pragma unroll
        for (int mt = 0; mt < 4; ++mt)
            af[mt] = *(const bf16x8*)(smem + swzA(((mt * 8 + kt) << 10) + lane * 16));
#pragma unroll
        for (int mt = 0; mt < 4; ++mt)
#pragma unroll
            for (int nti = 0; nti < 4; ++nti)
                acc[mt][nti] = __builtin_amdgcn_mfma_f32_16x16x32_bf16(
                    af[mt], bw[nti], acc[mt][nti], 0, 0, 0);
    }
    __syncthreads();   // bar1: A-frags consumed; region may be overwritten

    // write H -> LDS Hs[f][s] bf16 (swz), mask f<250; wave 3 extracts a_s/a_d.
    {
#pragma unroll
        for (int mt = 0; mt < 4; ++mt) {
            int s0 = mt * 16 + fh * 4;
#pragma unroll
            for (int nti = 0; nti < 4; ++nti) {
                int f = w * 64 + nti * 16 + fl;
                if (f < F_DIM) {
                    f32x4 v = acc[mt][nti];
                    bf16x4 hv = { (bf16)v.x, (bf16)v.y, (bf16)v.z, (bf16)v.w };
                    *(bf16x4*)(smem + swz(f * 128 + s0 * 2)) = hv;
                }
            }
        }
        if (w == 3 && (fl == 10 || fl == 11)) {
            float* dst = (float*)(smem + (fl == 10 ? OFF_AS : OFF_AD));
#pragma unroll
            for (int mt = 0; mt < 4; ++mt) {
                f32x4 v = acc[mt][3];
#pragma unroll
                for (int i = 0; i < 4; ++i) dst[mt * 16 + fh * 4 + i] = v[i];
            }
        }
    }
    __syncthreads();   // bar2: Hs + AS/AD visible

    // ---- softmax directly into GEMM2 A-frag registers (per wave) ----
    // lane (fh,fl) holds alpha[d=mt*16+fl][s=ks*32+fh*8+j], j=0..7.
    // Row max/sum reduced across the 4 fh-groups via shfl_xor 16/32.
    bf16x8 aal[4][2];
    {
        const float* AS  = (const float*)(smem + OFF_AS);
        const float* ADp = (const float*)(smem + OFF_AD);
        f32x4 s0 = *(const f32x4*)(AS + fh * 8);
        f32x4 s1 = *(const f32x4*)(AS + fh * 8 + 4);
        f32x4 s2 = *(const f32x4*)(AS + 32 + fh * 8);
        f32x4 s3 = *(const f32x4*)(AS + 32 + fh * 8 + 4);
#pragma unroll
        for (int mt = 0; mt < 4; ++mt) {
            float ad_v = ADp[mt * 16 + fl];
            float le[16];
#pragma unroll
            for (int k = 0; k < 4; ++k) {
                float e;
                e = s0[k] + ad_v; le[k]      = (e > 0.f) ? e : NEG_SLOPE * e;
                e = s1[k] + ad_v; le[4 + k]  = (e > 0.f) ? e : NEG_SLOPE * e;
                e = s2[k] + ad_v; le[8 + k]  = (e > 0.f) ? e : NEG_SLOPE * e;
                e = s3[k] + ad_v; le[12 + k] = (e > 0.f) ? e : NEG_SLOPE * e;
            }
            if (fh == 3) le[15] = -3.0e38f;   // s=63 excluded (63 sources)
            float md = le[0];
#pragma unroll
            for (int k = 1; k < 16; ++k) md = fmaxf(md, le[k]);
            md = fmaxf(md, __shfl_xor(md, 16));
            md = fmaxf(md, __shfl_xor(md, 32));
            float p[16], sum = 0.f;
#pragma unroll
            for (int k = 0; k < 16; ++k) { p[k] = __expf(le[k] - md); sum += p[k]; }
            sum += __shfl_xor(sum, 16);
            sum += __shfl_xor(sum, 32);
            float rz = 1.f / sum;
            bf16x8 a0, a1;
#pragma unroll
            for (int k = 0; k < 8; ++k) {
                a0[k] = (bf16)(p[k] * rz);
                a1[k] = (bf16)(p[8 + k] * rz);
            }
            aal[mt][0] = a0;
            aal[mt][1] = a1;
        }
    }

    // ---- GEMM2: out[64][256] = alpha[64][64] @ Hs[64][256] ----
    f32x4 acc2[4][4];
#pragma unroll
    for (int mt = 0; mt < 4; ++mt)
#pragma unroll
        for (int nti = 0; nti < 4; ++nti)
            acc2[mt][nti] = (f32x4){0.f, 0.f, 0.f, 0.f};
#pragma unroll
    for (int ks = 0; ks < 2; ++ks) {
        int kk = ks * 32 + fh * 8;
        bf16x8 hbf[4];
#pragma unroll
        for (int nti = 0; nti < 4; ++nti) {
            int f = w * 64 + nti * 16 + fl;
            hbf[nti] = *(const bf16x8*)(smem + swz(f * 128 + kk * 2));
        }
#pragma unroll
        for (int mt = 0; mt < 4; ++mt)
#pragma unroll
            for (int nti = 0; nti < 4; ++nti)
                acc2[mt][nti] = __builtin_amdgcn_mfma_f32_16x16x32_bf16(
                    aal[mt][ks], hbf[nti], acc2[mt][nti], 0, 0, 0);
    }

    // epilogue: + bias, store fp32, mask r<63 / f<250
    float* ob = out + (size_t)b * (C_NODES * F_DIM);
#pragma unroll
    for (int mt = 0; mt < 4; ++mt) {
#pragma unroll
        for (int i = 0; i < 4; ++i) {
            int r = mt * 16 + fh * 4 + i;
            if (r < C_NODES) {
#pragma unroll
                for (int nti = 0; nti < 4; ++nti) {
                    int f = w * 64 + nti * 16 + fl;
                    if (f < F_DIM) ob[r * F_DIM + f] = acc2[mt][nti][i] + bv[nti];
                }
            }
        }
    }
}

extern "C" void kernel_launch(void* const* d_in, const int* in_sizes, int n_in,
                              void* d_out, int out_size, void* d_ws, size_t ws_size,
                              hipStream_t stream) {
    const float* x       = (const float*)d_in[0];
    const float* W       = (const float*)d_in[1];
    const float* att_src = (const float*)d_in[2];
    const float* att_dst = (const float*)d_in[3];
    const float* bias    = (const float*)d_in[4];
    float* out = (float*)d_out;
    bf16* Wp = (bf16*)d_ws;   // 65536 bf16 = 128 KB packed W (+score cols)

    gat_prep<<<256, 256, 0, stream>>>(W, att_src, att_dst, Wp);
    gat_main<<<4096, 256, 0, stream>>>(x, Wp, bias, out);
}

// Round 7
// 180.605 us; speedup vs baseline: 1.0280x; 1.0280x over previous
//
#include <hip/hip_runtime.h>
#include <hip/hip_bf16.h>

typedef __bf16 bf16;
typedef __attribute__((ext_vector_type(8))) __bf16 bf16x8;
typedef __attribute__((ext_vector_type(4))) __bf16 bf16x4;
typedef __attribute__((ext_vector_type(2))) __bf16 bf16x2;
typedef __attribute__((ext_vector_type(4))) float f32x4;

#define C_NODES 63
#define F_DIM   250
#define NEG_SLOPE 0.2f

// LDS layout (32768 B):
//   [0, 32768)     A-fragments of X (GEMM1, swzA-swizzled), then reused as
//                  Hs[f][s] bf16 (f<250, swz-swizzled row-locally).
//   [32000,32256)  AS: a_s[64] f32   (bytes 250*128.. — beyond Hs rows,
//   [32256,32512)  AD: a_d[64] f32    written only after bar1)
#define OFF_AS    32000
#define OFF_AD    32256
#define LDS_BYTES 32768

// Hs swizzle: XOR f&7 into bank bits 4-6; row-local (128B rows).
__device__ __forceinline__ int swz(int a) { return a ^ ((a >> 3) & 0x70); }
// A-frag swizzle: XOR (dl-hi ^ kt-lo) into bits 4-5 and kt-bit2 into bit 6.
// Makes the row-major staging writes bank-uniform; reads stay per-lane
// bijective. Key bits (8-12) unmodified -> bijection, same formula both sides.
__device__ __forceinline__ int swzA(int a) {
    return a ^ ((((a >> 8) & 3) ^ ((a >> 10) & 3)) << 4) ^ (((a >> 12) & 1) << 6);
}

// Pack W (250x250 f32) into bf16 MFMA-B fragment order, padded to 256x256.
// Columns 250/251 hold ws = W@att_src and wd = W@att_dst, so GEMM1 emits the
// per-node scores a_s, a_d directly. Rows k>=250 are zero (kills A-garbage).
extern "C" __global__ __launch_bounds__(256)
void gat_prep(const float* __restrict__ W, const float* __restrict__ att_src,
              const float* __restrict__ att_dst, bf16* __restrict__ Wp) {
    int i = blockIdx.x * 256 + threadIdx.x;   // 0..65535
    int tile = i >> 9;
    int ln   = (i >> 3) & 63;
    int j    = i & 7;
    int kt = tile >> 4, nt = tile & 15;
    int k = kt * 32 + (ln >> 4) * 8 + j;
    int n = nt * 16 + (ln & 15);
    float v = 0.f;
    if (k < F_DIM) {
        if (n < F_DIM) {
            v = W[k * F_DIM + n];
        } else if (n == F_DIM || n == F_DIM + 1) {
            const float* att = (n == F_DIM) ? att_src : att_dst;
            float s = 0.f;
            for (int o = 0; o < F_DIM; ++o) s = fmaf(W[k * F_DIM + o], att[o], s);
            v = s;
        }
    }
    Wp[i] = (bf16)v;
}

extern "C" __global__ __launch_bounds__(256, 4)
void gat_main(const float* __restrict__ x, const bf16* __restrict__ Wp,
              const float* __restrict__ bias, float* __restrict__ out)
{
    __shared__ __align__(16) unsigned char smem[LDS_BYTES];
    const int tid  = threadIdx.x;
    const int lane = tid & 63;
    const int w    = tid >> 6;        // wave id 0..3 -> owns 64 output columns
    const int b    = blockIdx.x;
    const int fl   = lane & 15;
    const int fh   = lane >> 4;

    const bf16x8* wpv = (const bf16x8*)Wp;

    // bias preload (overlaps staging)
    float bv[4];
#pragma unroll
    for (int nti = 0; nti < 4; ++nti) {
        int f = w * 64 + nti * 16 + fl;
        bv[nti] = (f < F_DIM) ? bias[f] : 0.f;
    }

    // NaN-guard: zero the only A-frag slots the scatter never writes.
    if (tid < 64) {
        // c in 250..255 tail: tile (mt,7), dl=48+(r&15), bytes 4..15
        int base = swzA((((tid >> 4) * 8 + 7) << 10) + (48 + (tid & 15)) * 16);
        *(unsigned int*)(smem + base + 4) = 0u;
        *(unsigned long long*)(smem + base + 8) = 0ull;
    } else if (tid < 96) {
        // row r=63: tile (3,kt), dl=((g&3)<<4)|15, full 16 B
        int idx = tid - 64;
        int base = swzA(((24 + (idx >> 2)) << 10) + ((((idx & 3) << 4) | 15) * 16));
        *(f32x4*)(smem + base) = (f32x4){0.f, 0.f, 0.f, 0.f};
    }

    // stage X_b -> bf16 A-fragments (swzA): 63 rows x 32 col-groups,
    // idx = r*32+g; 16B ds_write per full group, bank-conflict-free via swzA.
    {
        const float* xb = x + (size_t)b * (C_NODES * F_DIM);
#pragma unroll
        for (int it = 0; it < 8; ++it) {
            int idx = tid + it * 256;
            if (idx < 2016) {
                int r = idx >> 5, g = idx & 31;
                const float* src = xb + r * F_DIM + g * 8;
                int dl = (r & 15) | ((g & 3) << 4);
                int base = swzA((((r >> 4) * 8 + (g >> 2)) << 10) + dl * 16);
                if (g < 31) {
                    float2 v0 = *(const float2*)(src);
                    float2 v1 = *(const float2*)(src + 2);
                    float2 v2 = *(const float2*)(src + 4);
                    float2 v3 = *(const float2*)(src + 6);
                    bf16x8 pk = { (bf16)v0.x, (bf16)v0.y, (bf16)v1.x, (bf16)v1.y,
                                  (bf16)v2.x, (bf16)v2.y, (bf16)v3.x, (bf16)v3.y };
                    *(bf16x8*)(smem + base) = pk;
                } else {
                    // tail: only c=248,249 valid (j=0,1); j>=2 zeroed by guard
                    float2 v0 = *(const float2*)(src);
                    bf16x2 pk = { (bf16)v0.x, (bf16)v0.y };
                    *(bf16x2*)(smem + base) = pk;
                }
            }
        }
    }
    __syncthreads();   // bar0: A-frags ready

    // ---- GEMM1: H'[64][256] = X @ Wp ; cols 250/251 are a_s/a_d ----
    f32x4 acc[4][4];
#pragma unroll
    for (int mt = 0; mt < 4; ++mt)
#pragma unroll
        for (int nti = 0; nti < 4; ++nti)
            acc[mt][nti] = (f32x4){0.f, 0.f, 0.f, 0.f};
#pragma unroll 2
    for (int kt = 0; kt < 8; ++kt) {
        bf16x8 af[4], bw[4];
#pragma unroll
        for (int nti = 0; nti < 4; ++nti)
            bw[nti] = wpv[(kt * 16 + (w * 4 + nti)) * 64 + lane];
#pragma unroll
        for (int mt = 0; mt < 4; ++mt)
            af[mt] = *(const bf16x8*)(smem + swzA(((mt * 8 + kt) << 10) + lane * 16));
#pragma unroll
        for (int mt = 0; mt < 4; ++mt)
#pragma unroll
            for (int nti = 0; nti < 4; ++nti)
                acc[mt][nti] = __builtin_amdgcn_mfma_f32_16x16x32_bf16(
                    af[mt], bw[nti], acc[mt][nti], 0, 0, 0);
    }
    __syncthreads();   // bar1: A-frags consumed; region may be overwritten

    // write H -> LDS Hs[f][s] bf16 (swz), mask f<250; wave 3 extracts a_s/a_d.
    {
#pragma unroll
        for (int mt = 0; mt < 4; ++mt) {
            int s0 = mt * 16 + fh * 4;
#pragma unroll
            for (int nti = 0; nti < 4; ++nti) {
                int f = w * 64 + nti * 16 + fl;
                if (f < F_DIM) {
                    f32x4 v = acc[mt][nti];
                    bf16x4 hv = { (bf16)v.x, (bf16)v.y, (bf16)v.z, (bf16)v.w };
                    *(bf16x4*)(smem + swz(f * 128 + s0 * 2)) = hv;
                }
            }
        }
        if (w == 3 && (fl == 10 || fl == 11)) {
            float* dst = (float*)(smem + (fl == 10 ? OFF_AS : OFF_AD));
#pragma unroll
            for (int mt = 0; mt < 4; ++mt) {
                f32x4 v = acc[mt][3];
#pragma unroll
                for (int i = 0; i < 4; ++i) dst[mt * 16 + fh * 4 + i] = v[i];
            }
        }
    }
    __syncthreads();   // bar2: Hs + AS/AD visible

    // ---- softmax directly into GEMM2 A-frag registers (per wave) ----
    // lane (fh,fl) holds alpha[d=mt*16+fl][s=ks*32+fh*8+j], j=0..7.
    // Row max/sum reduced across the 4 fh-groups via shfl_xor 16/32.
    bf16x8 aal[4][2];
    {
        const float* AS  = (const float*)(smem + OFF_AS);
        const float* ADp = (const float*)(smem + OFF_AD);
        f32x4 s0 = *(const f32x4*)(AS + fh * 8);
        f32x4 s1 = *(const f32x4*)(AS + fh * 8 + 4);
        f32x4 s2 = *(const f32x4*)(AS + 32 + fh * 8);
        f32x4 s3 = *(const f32x4*)(AS + 32 + fh * 8 + 4);
#pragma unroll
        for (int mt = 0; mt < 4; ++mt) {
            float ad_v = ADp[mt * 16 + fl];
            float le[16];
#pragma unroll
            for (int k = 0; k < 4; ++k) {
                float e;
                e = s0[k] + ad_v; le[k]      = (e > 0.f) ? e : NEG_SLOPE * e;
                e = s1[k] + ad_v; le[4 + k]  = (e > 0.f) ? e : NEG_SLOPE * e;
                e = s2[k] + ad_v; le[8 + k]  = (e > 0.f) ? e : NEG_SLOPE * e;
                e = s3[k] + ad_v; le[12 + k] = (e > 0.f) ? e : NEG_SLOPE * e;
            }
            if (fh == 3) le[15] = -3.0e38f;   // s=63 excluded (63 sources)
            float md = le[0];
#pragma unroll
            for (int k = 1; k < 16; ++k) md = fmaxf(md, le[k]);
            md = fmaxf(md, __shfl_xor(md, 16));
            md = fmaxf(md, __shfl_xor(md, 32));
            float p[16], sum = 0.f;
#pragma unroll
            for (int k = 0; k < 16; ++k) { p[k] = __expf(le[k] - md); sum += p[k]; }
            sum += __shfl_xor(sum, 16);
            sum += __shfl_xor(sum, 32);
            float rz = 1.f / sum;
            bf16x8 a0, a1;
#pragma unroll
            for (int k = 0; k < 8; ++k) {
                a0[k] = (bf16)(p[k] * rz);
                a1[k] = (bf16)(p[8 + k] * rz);
            }
            aal[mt][0] = a0;
            aal[mt][1] = a1;
        }
    }

    // ---- GEMM2: out[64][256] = alpha[64][64] @ Hs[64][256] ----
    f32x4 acc2[4][4];
#pragma unroll
    for (int mt = 0; mt < 4; ++mt)
#pragma unroll
        for (int nti = 0; nti < 4; ++nti)
            acc2[mt][nti] = (f32x4){0.f, 0.f, 0.f, 0.f};
#pragma unroll
    for (int ks = 0; ks < 2; ++ks) {
        int kk = ks * 32 + fh * 8;
        bf16x8 hbf[4];
#pragma unroll
        for (int nti = 0; nti < 4; ++nti) {
            int f = w * 64 + nti * 16 + fl;
            hbf[nti] = *(const bf16x8*)(smem + swz(f * 128 + kk * 2));
        }
#pragma unroll
        for (int mt = 0; mt < 4; ++mt)
#pragma unroll
            for (int nti = 0; nti < 4; ++nti)
                acc2[mt][nti] = __builtin_amdgcn_mfma_f32_16x16x32_bf16(
                    aal[mt][ks], hbf[nti], acc2[mt][nti], 0, 0, 0);
    }

    // epilogue: + bias, store fp32, mask r<63 / f<250
    float* ob = out + (size_t)b * (C_NODES * F_DIM);
#pragma unroll
    for (int mt = 0; mt < 4; ++mt) {
#pragma unroll
        for (int i = 0; i < 4; ++i) {
            int r = mt * 16 + fh * 4 + i;
            if (r < C_NODES) {
#pragma unroll
                for (int nti = 0; nti < 4; ++nti) {
                    int f = w * 64 + nti * 16 + fl;
                    if (f < F_DIM) ob[r * F_DIM + f] = acc2[mt][nti][i] + bv[nti];
                }
            }
        }
    }
}

extern "C" void kernel_launch(void* const* d_in, const int* in_sizes, int n_in,
                              void* d_out, int out_size, void* d_ws, size_t ws_size,
                              hipStream_t stream) {
    const float* x       = (const float*)d_in[0];
    const float* W       = (const float*)d_in[1];
    const float* att_src = (const float*)d_in[2];
    const float* att_dst = (const float*)d_in[3];
    const float* bias    = (const float*)d_in[4];
    float* out = (float*)d_out;
    bf16* Wp = (bf16*)d_ws;   // 65536 bf16 = 128 KB packed W (+score cols)

    gat_prep<<<256, 256, 0, stream>>>(W, att_src, att_dst, Wp);
    gat_main<<<4096, 256, 0, stream>>>(x, Wp, bias, out);
}

// Round 8
// 154.644 us; speedup vs baseline: 1.2006x; 1.1679x over previous
//
#include <hip/hip_runtime.h>
#include <hip/hip_bf16.h>

typedef __bf16 bf16;
typedef __attribute__((ext_vector_type(8))) __bf16 bf16x8;
typedef __attribute__((ext_vector_type(4))) __bf16 bf16x4;
typedef __attribute__((ext_vector_type(2))) __bf16 bf16x2;
typedef __attribute__((ext_vector_type(4))) float f32x4;

#define C_NODES 63
#define F_DIM   250
#define NEG_SLOPE 0.2f

// LDS layout (32768 B):
//   [0, 32768)     A-fragments of X (GEMM1, swzA-swizzled), then reused as
//                  Hs[f][s] bf16 (f<250, swz-swizzled row-locally).
//   [32000,32256)  AS: a_s[64] f32   (bytes 250*128.. — beyond Hs rows,
//   [32256,32512)  AD: a_d[64] f32    written only after bar1)
#define OFF_AS    32000
#define OFF_AD    32256
#define LDS_BYTES 32768

// Hs swizzle: XOR f&7 into bank bits 4-6; row-local (128B rows).
__device__ __forceinline__ int swz(int a) { return a ^ ((a >> 3) & 0x70); }
// A-frag swizzle: XOR (dl-hi ^ kt-lo) into bits 4-5 and kt-bit2 into bit 6.
// Makes the row-major staging writes bank-uniform; reads stay per-lane
// bijective. Key bits (8-12) unmodified -> bijection, same formula both sides.
__device__ __forceinline__ int swzA(int a) {
    return a ^ ((((a >> 8) & 3) ^ ((a >> 10) & 3)) << 4) ^ (((a >> 12) & 1) << 6);
}

// Pack W (250x250 f32) into bf16 MFMA-B fragment order, padded to 256x256.
// Columns 250/251 hold ws = W@att_src and wd = W@att_dst, so GEMM1 emits the
// per-node scores a_s, a_d directly. Rows k>=250 are zero (kills A-garbage).
extern "C" __global__ __launch_bounds__(256)
void gat_prep(const float* __restrict__ W, const float* __restrict__ att_src,
              const float* __restrict__ att_dst, bf16* __restrict__ Wp) {
    int i = blockIdx.x * 256 + threadIdx.x;   // 0..65535
    int tile = i >> 9;
    int ln   = (i >> 3) & 63;
    int j    = i & 7;
    int kt = tile >> 4, nt = tile & 15;
    int k = kt * 32 + (ln >> 4) * 8 + j;
    int n = nt * 16 + (ln & 15);
    float v = 0.f;
    if (k < F_DIM) {
        if (n < F_DIM) {
            v = W[k * F_DIM + n];
        } else if (n == F_DIM || n == F_DIM + 1) {
            const float* att = (n == F_DIM) ? att_src : att_dst;
            float s = 0.f;
            for (int o = 0; o < F_DIM; ++o) s = fmaf(W[k * F_DIM + o], att[o], s);
            v = s;
        }
    }
    Wp[i] = (bf16)v;
}

extern "C" __global__ __launch_bounds__(256, 4)
void gat_main(const float* __restrict__ x, const bf16* __restrict__ Wp,
              const float* __restrict__ bias, float* __restrict__ out)
{
    __shared__ __align__(16) unsigned char smem[LDS_BYTES];
    const int tid  = threadIdx.x;
    const int lane = tid & 63;
    const int w    = tid >> 6;        // wave id 0..3 -> owns 64 output columns
    const int b    = blockIdx.x;
    const int fl   = lane & 15;
    const int fh   = lane >> 4;

    const bf16x8* wpv = (const bf16x8*)Wp;

    // NaN-guard: zero the only A-frag slots the scatter never writes.
    if (tid < 64) {
        // c in 250..255 tail: tile (mt,7), dl=48+(r&15), bytes 4..15
        int base = swzA((((tid >> 4) * 8 + 7) << 10) + (48 + (tid & 15)) * 16);
        *(unsigned int*)(smem + base + 4) = 0u;
        *(unsigned long long*)(smem + base + 8) = 0ull;
    } else if (tid < 96) {
        // row r=63: tile (3,kt), dl=((g&3)<<4)|15, full 16 B
        int idx = tid - 64;
        int base = swzA(((24 + (idx >> 2)) << 10) + ((((idx & 3) << 4) | 15) * 16));
        *(f32x4*)(smem + base) = (f32x4){0.f, 0.f, 0.f, 0.f};
    }

    // stage X_b -> bf16 A-fragments (swzA): 63 rows x 32 col-groups,
    // idx = r*32+g; 16B ds_write per full group, bank-conflict-free via swzA.
    {
        const float* xb = x + (size_t)b * (C_NODES * F_DIM);
#pragma unroll
        for (int it = 0; it < 8; ++it) {
            int idx = tid + it * 256;
            if (idx < 2016) {
                int r = idx >> 5, g = idx & 31;
                const float* src = xb + r * F_DIM + g * 8;
                int dl = (r & 15) | ((g & 3) << 4);
                int base = swzA((((r >> 4) * 8 + (g >> 2)) << 10) + dl * 16);
                if (g < 31) {
                    float2 v0 = *(const float2*)(src);
                    float2 v1 = *(const float2*)(src + 2);
                    float2 v2 = *(const float2*)(src + 4);
                    float2 v3 = *(const float2*)(src + 6);
                    bf16x8 pk = { (bf16)v0.x, (bf16)v0.y, (bf16)v1.x, (bf16)v1.y,
                                  (bf16)v2.x, (bf16)v2.y, (bf16)v3.x, (bf16)v3.y };
                    *(bf16x8*)(smem + base) = pk;
                } else {
                    // tail: only c=248,249 valid (j=0,1); j>=2 zeroed by guard
                    float2 v0 = *(const float2*)(src);
                    bf16x2 pk = { (bf16)v0.x, (bf16)v0.y };
                    *(bf16x2*)(smem + base) = pk;
                }
            }
        }
    }
    __syncthreads();   // bar0: A-frags ready

    // ---- GEMM1: H'[64][256] = X @ Wp ; cols 250/251 are a_s/a_d ----
    f32x4 acc[4][4];
#pragma unroll
    for (int mt = 0; mt < 4; ++mt)
#pragma unroll
        for (int nti = 0; nti < 4; ++nti)
            acc[mt][nti] = (f32x4){0.f, 0.f, 0.f, 0.f};
#pragma unroll 2
    for (int kt = 0; kt < 8; ++kt) {
        bf16x8 af[4], bw[4];
#pragma unroll
        for (int nti = 0; nti < 4; ++nti)
            bw[nti] = wpv[(kt * 16 + (w * 4 + nti)) * 64 + lane];
#pragma unroll
        for (int mt = 0; mt < 4; ++mt)
            af[mt] = *(const bf16x8*)(smem + swzA(((mt * 8 + kt) << 10) + lane * 16));
#pragma unroll
        for (int mt = 0; mt < 4; ++mt)
#pragma unroll
            for (int nti = 0; nti < 4; ++nti)
                acc[mt][nti] = __builtin_amdgcn_mfma_f32_16x16x32_bf16(
                    af[mt], bw[nti], acc[mt][nti], 0, 0, 0);
    }
    __syncthreads();   // bar1: A-frags consumed; region may be overwritten

    // write H -> LDS Hs[f][s] bf16 (swz), mask f<250; wave 3 extracts a_s/a_d.
    {
#pragma unroll
        for (int mt = 0; mt < 4; ++mt) {
            int s0 = mt * 16 + fh * 4;
#pragma unroll
            for (int nti = 0; nti < 4; ++nti) {
                int f = w * 64 + nti * 16 + fl;
                if (f < F_DIM) {
                    f32x4 v = acc[mt][nti];
                    bf16x4 hv = { (bf16)v.x, (bf16)v.y, (bf16)v.z, (bf16)v.w };
                    *(bf16x4*)(smem + swz(f * 128 + s0 * 2)) = hv;
                }
            }
        }
        if (w == 3 && (fl == 10 || fl == 11)) {
            float* dst = (float*)(smem + (fl == 10 ? OFF_AS : OFF_AD));
#pragma unroll
            for (int mt = 0; mt < 4; ++mt) {
                f32x4 v = acc[mt][3];
#pragma unroll
                for (int i = 0; i < 4; ++i) dst[mt * 16 + fh * 4 + i] = v[i];
            }
        }
    }
    __syncthreads();   // bar2: Hs + AS/AD visible

    // ---- softmax directly into GEMM2 A-frag registers (per wave) ----
    // lane (fh,fl) holds alpha[d=mt*16+fl][s=ks*32+fh*8+j], j=0..7.
    // Row max/sum reduced across the 4 fh-groups via shfl_xor 16/32.
    // Register-lean: single p[16] array reused lrelu->exp->scaled.
    bf16x8 aal[4][2];
    {
        const float* AS  = (const float*)(smem + OFF_AS);
        const float* ADp = (const float*)(smem + OFF_AD);
        f32x4 s0 = *(const f32x4*)(AS + fh * 8);
        f32x4 s1 = *(const f32x4*)(AS + fh * 8 + 4);
        f32x4 s2 = *(const f32x4*)(AS + 32 + fh * 8);
        f32x4 s3 = *(const f32x4*)(AS + 32 + fh * 8 + 4);
#pragma unroll
        for (int mt = 0; mt < 4; ++mt) {
            float ad_v = ADp[mt * 16 + fl];
            float p[16];
#pragma unroll
            for (int k = 0; k < 4; ++k) {
                float e;
                e = s0[k] + ad_v; p[k]      = (e > 0.f) ? e : NEG_SLOPE * e;
                e = s1[k] + ad_v; p[4 + k]  = (e > 0.f) ? e : NEG_SLOPE * e;
                e = s2[k] + ad_v; p[8 + k]  = (e > 0.f) ? e : NEG_SLOPE * e;
                e = s3[k] + ad_v; p[12 + k] = (e > 0.f) ? e : NEG_SLOPE * e;
            }
            if (fh == 3) p[15] = -3.0e38f;   // s=63 excluded (63 sources)
            float md = p[0];
#pragma unroll
            for (int k = 1; k < 16; ++k) md = fmaxf(md, p[k]);
            md = fmaxf(md, __shfl_xor(md, 16));
            md = fmaxf(md, __shfl_xor(md, 32));
            float sum = 0.f;
#pragma unroll
            for (int k = 0; k < 16; ++k) { p[k] = __expf(p[k] - md); sum += p[k]; }
            sum += __shfl_xor(sum, 16);
            sum += __shfl_xor(sum, 32);
            float rz = 1.f / sum;
            bf16x8 a0, a1;
#pragma unroll
            for (int k = 0; k < 8; ++k) {
                a0[k] = (bf16)(p[k] * rz);
                a1[k] = (bf16)(p[8 + k] * rz);
            }
            aal[mt][0] = a0;
            aal[mt][1] = a1;
        }
    }

    // ---- GEMM2: out[64][256] = alpha[64][64] @ Hs[64][256] ----
    f32x4 acc2[4][4];
#pragma unroll
    for (int mt = 0; mt < 4; ++mt)
#pragma unroll
        for (int nti = 0; nti < 4; ++nti)
            acc2[mt][nti] = (f32x4){0.f, 0.f, 0.f, 0.f};
#pragma unroll
    for (int ks = 0; ks < 2; ++ks) {
        int kk = ks * 32 + fh * 8;
        bf16x8 hbf[4];
#pragma unroll
        for (int nti = 0; nti < 4; ++nti) {
            int f = w * 64 + nti * 16 + fl;
            hbf[nti] = *(const bf16x8*)(smem + swz(f * 128 + kk * 2));
        }
#pragma unroll
        for (int mt = 0; mt < 4; ++mt)
#pragma unroll
            for (int nti = 0; nti < 4; ++nti)
                acc2[mt][nti] = __builtin_amdgcn_mfma_f32_16x16x32_bf16(
                    aal[mt][ks], hbf[nti], acc2[mt][nti], 0, 0, 0);
    }

    // epilogue: + bias (loaded here, L2-hot; frees 4 regs during main phases),
    // store fp32, mask r<63 / f<250
    float bv[4];
#pragma unroll
    for (int nti = 0; nti < 4; ++nti) {
        int f = w * 64 + nti * 16 + fl;
        bv[nti] = (f < F_DIM) ? bias[f] : 0.f;
    }
    float* ob = out + (size_t)b * (C_NODES * F_DIM);
#pragma unroll
    for (int mt = 0; mt < 4; ++mt) {
#pragma unroll
        for (int i = 0; i < 4; ++i) {
            int r = mt * 16 + fh * 4 + i;
            if (r < C_NODES) {
#pragma unroll
                for (int nti = 0; nti < 4; ++nti) {
                    int f = w * 64 + nti * 16 + fl;
                    if (f < F_DIM) ob[r * F_DIM + f] = acc2[mt][nti][i] + bv[nti];
                }
            }
        }
    }
}

extern "C" void kernel_launch(void* const* d_in, const int* in_sizes, int n_in,
                              void* d_out, int out_size, void* d_ws, size_t ws_size,
                              hipStream_t stream) {
    const float* x       = (const float*)d_in[0];
    const float* W       = (const float*)d_in[1];
    const float* att_src = (const float*)d_in[2];
    const float* att_dst = (const float*)d_in[3];
    const float* bias    = (const float*)d_in[4];
    float* out = (float*)d_out;
    bf16* Wp = (bf16*)d_ws;   // 65536 bf16 = 128 KB packed W (+score cols)

    gat_prep<<<256, 256, 0, stream>>>(W, att_src, att_dst, Wp);
    gat_main<<<4096, 256, 0, stream>>>(x, Wp, bias, out);
}

// Round 9
// 145.501 us; speedup vs baseline: 1.2760x; 1.0628x over previous
//
#include <hip/hip_runtime.h>
#include <hip/hip_bf16.h>

typedef __bf16 bf16;
typedef __attribute__((ext_vector_type(8))) __bf16 bf16x8;
typedef __attribute__((ext_vector_type(4))) __bf16 bf16x4;
typedef __attribute__((ext_vector_type(2))) __bf16 bf16x2;
typedef __attribute__((ext_vector_type(4))) float f32x4;

#define C_NODES 63
#define F_DIM   250
#define NEG_SLOPE 0.2f

// LDS layout (40960 B = 4 blocks/CU at 160 KiB):
//   [0, 32768)     A-fragments of X (GEMM1, swzA), then reused as Hs[f][s]
//                  bf16 (f<250, swz row-local).
//   [32000,32256)  AS: a_s[64] f32   (inside Hs rows 250..255, never written
//   [32256,32512)  AD: a_d[64] f32    by the f<250-masked Hs stores)
//   [32768,40960)  alpha [64 d][64 s] bf16 (swz)
#define OFF_AS    32000
#define OFF_AD    32256
#define OFF_ALPHA 32768
#define LDS_BYTES 40960

// Hs/alpha swizzle: XOR row&7 into bank bits 4-6; row-local (128B rows).
__device__ __forceinline__ int swz(int a) { return a ^ ((a >> 3) & 0x70); }
// A-frag swizzle: bank-uniform staging writes, bijective reads.
__device__ __forceinline__ int swzA(int a) {
    return a ^ ((((a >> 8) & 3) ^ ((a >> 10) & 3)) << 4) ^ (((a >> 12) & 1) << 6);
}

// Pack W (250x250 f32) into bf16 MFMA-B fragment order, padded to 256x256.
// Columns 250/251 hold ws = W@att_src and wd = W@att_dst, so GEMM1 emits the
// per-node scores a_s, a_d directly. Rows k>=250 are zero (kills A-garbage).
extern "C" __global__ __launch_bounds__(256)
void gat_prep(const float* __restrict__ W, const float* __restrict__ att_src,
              const float* __restrict__ att_dst, bf16* __restrict__ Wp) {
    int i = blockIdx.x * 256 + threadIdx.x;   // 0..65535
    int tile = i >> 9;
    int ln   = (i >> 3) & 63;
    int j    = i & 7;
    int kt = tile >> 4, nt = tile & 15;
    int k = kt * 32 + (ln >> 4) * 8 + j;
    int n = nt * 16 + (ln & 15);
    float v = 0.f;
    if (k < F_DIM) {
        if (n < F_DIM) {
            v = W[k * F_DIM + n];
        } else if (n == F_DIM || n == F_DIM + 1) {
            const float* att = (n == F_DIM) ? att_src : att_dst;
            float s = 0.f;
            for (int o = 0; o < F_DIM; ++o) s = fmaf(W[k * F_DIM + o], att[o], s);
            v = s;
        }
    }
    Wp[i] = (bf16)v;
}

// 512 threads = 8 waves; wave w owns output cols [w*32, w*32+32).
extern "C" __global__ __launch_bounds__(512, 8)
void gat_main(const float* __restrict__ x, const bf16* __restrict__ Wp,
              const float* __restrict__ bias, float* __restrict__ out)
{
    __shared__ __align__(16) unsigned char smem[LDS_BYTES];
    const int tid  = threadIdx.x;
    const int lane = tid & 63;
    const int w    = tid >> 6;        // wave id 0..7
    const int b    = blockIdx.x;
    const int fl   = lane & 15;
    const int fh   = lane >> 4;

    const bf16x8* wpv = (const bf16x8*)Wp;

    // NaN-guard: zero the only A-frag slots the scatter never writes.
    if (tid < 64) {
        // c in 250..255 tail: tile (mt,7), dl=48+(r&15), bytes 4..15
        int base = swzA((((tid >> 4) * 8 + 7) << 10) + (48 + (tid & 15)) * 16);
        *(unsigned int*)(smem + base + 4) = 0u;
        *(unsigned long long*)(smem + base + 8) = 0ull;
    } else if (tid < 96) {
        // row r=63: tile (3,kt), dl=((g&3)<<4)|15, full 16 B
        int idx = tid - 64;
        int base = swzA(((24 + (idx >> 2)) << 10) + ((((idx & 3) << 4) | 15) * 16));
        *(f32x4*)(smem + base) = (f32x4){0.f, 0.f, 0.f, 0.f};
    }

    // stage X_b -> bf16 A-fragments (swzA): 63 rows x 32 col-groups.
    {
        const float* xb = x + (size_t)b * (C_NODES * F_DIM);
#pragma unroll
        for (int it = 0; it < 4; ++it) {
            int idx = tid + it * 512;
            if (idx < 2016) {
                int r = idx >> 5, g = idx & 31;
                const float* src = xb + r * F_DIM + g * 8;
                int dl = (r & 15) | ((g & 3) << 4);
                int base = swzA((((r >> 4) * 8 + (g >> 2)) << 10) + dl * 16);
                if (g < 31) {
                    float2 v0 = *(const float2*)(src);
                    float2 v1 = *(const float2*)(src + 2);
                    float2 v2 = *(const float2*)(src + 4);
                    float2 v3 = *(const float2*)(src + 6);
                    bf16x8 pk = { (bf16)v0.x, (bf16)v0.y, (bf16)v1.x, (bf16)v1.y,
                                  (bf16)v2.x, (bf16)v2.y, (bf16)v3.x, (bf16)v3.y };
                    *(bf16x8*)(smem + base) = pk;
                } else {
                    // tail: only c=248,249 valid; j>=2 zeroed by guard
                    float2 v0 = *(const float2*)(src);
                    bf16x2 pk = { (bf16)v0.x, (bf16)v0.y };
                    *(bf16x2*)(smem + base) = pk;
                }
            }
        }
    }
    __syncthreads();   // bar0: A-frags ready

    // ---- GEMM1: H'[64][256] = X @ Wp ; cols 250/251 are a_s/a_d ----
    // Rolled K-loop keeps live set ~60 regs; TLP (8 waves/SIMD) hides latency.
    f32x4 acc[4][2];
#pragma unroll
    for (int mt = 0; mt < 4; ++mt) {
        acc[mt][0] = (f32x4){0.f, 0.f, 0.f, 0.f};
        acc[mt][1] = (f32x4){0.f, 0.f, 0.f, 0.f};
    }
#pragma unroll 1
    for (int kt = 0; kt < 8; ++kt) {
        bf16x8 bw0 = wpv[(kt * 16 + w * 2)     * 64 + lane];
        bf16x8 bw1 = wpv[(kt * 16 + w * 2 + 1) * 64 + lane];
#pragma unroll
        for (int mt = 0; mt < 4; ++mt) {
            bf16x8 af = *(const bf16x8*)(smem + swzA(((mt * 8 + kt) << 10) + lane * 16));
            acc[mt][0] = __builtin_amdgcn_mfma_f32_16x16x32_bf16(af, bw0, acc[mt][0], 0, 0, 0);
            acc[mt][1] = __builtin_amdgcn_mfma_f32_16x16x32_bf16(af, bw1, acc[mt][1], 0, 0, 0);
        }
    }
    __syncthreads();   // bar1: A-frags consumed; region may be overwritten

    // write H -> LDS Hs[f][s] bf16 (swz), mask f<250; wave 7 extracts a_s/a_d.
    {
#pragma unroll
        for (int mt = 0; mt < 4; ++mt) {
            int s0 = mt * 16 + fh * 4;
#pragma unroll
            for (int nti = 0; nti < 2; ++nti) {
                int f = w * 32 + nti * 16 + fl;
                if (f < F_DIM) {
                    f32x4 v = acc[mt][nti];
                    bf16x4 hv = { (bf16)v.x, (bf16)v.y, (bf16)v.z, (bf16)v.w };
                    *(bf16x4*)(smem + swz(f * 128 + s0 * 2)) = hv;
                }
            }
        }
        if (w == 7 && (fl == 10 || fl == 11)) {     // cols 250 / 251
            float* dst = (float*)(smem + (fl == 10 ? OFF_AS : OFF_AD));
#pragma unroll
            for (int mt = 0; mt < 4; ++mt) {
                f32x4 v = acc[mt][1];
#pragma unroll
                for (int i = 0; i < 4; ++i) dst[mt * 16 + fh * 4 + i] = v[i];
            }
        }
    }
    __syncthreads();   // bar2: Hs + AS/AD visible

    // ---- softmax (block-wide, computed ONCE): thread=(d=tid>>3, c=tid&7),
    // 8 sources each; reduce across the 8 c-threads via shfl_xor 1/2/4. ----
    {
        const float* AS  = (const float*)(smem + OFF_AS);
        const float* ADp = (const float*)(smem + OFF_AD);
        int d = tid >> 3;
        int c = tid & 7;
        float ad_v = ADp[d];
        f32x4 a0 = *(const f32x4*)(AS + c * 8);
        f32x4 a1 = *(const f32x4*)(AS + c * 8 + 4);
        float p[8];
#pragma unroll
        for (int k = 0; k < 4; ++k) {
            float e;
            e = a0[k] + ad_v; p[k]     = (e > 0.f) ? e : NEG_SLOPE * e;
            e = a1[k] + ad_v; p[4 + k] = (e > 0.f) ? e : NEG_SLOPE * e;
        }
        if (c == 7) p[7] = -3.0e38f;   // s=63 excluded (63 sources)
        float md = p[0];
#pragma unroll
        for (int k = 1; k < 8; ++k) md = fmaxf(md, p[k]);
        md = fmaxf(md, __shfl_xor(md, 1));
        md = fmaxf(md, __shfl_xor(md, 2));
        md = fmaxf(md, __shfl_xor(md, 4));
        float sum = 0.f;
#pragma unroll
        for (int k = 0; k < 8; ++k) { p[k] = __expf(p[k] - md); sum += p[k]; }
        sum += __shfl_xor(sum, 1);
        sum += __shfl_xor(sum, 2);
        sum += __shfl_xor(sum, 4);
        float rz = 1.f / sum;
        bf16x8 pk;
#pragma unroll
        for (int k = 0; k < 8; ++k) pk[k] = (bf16)(p[k] * rz);
        *(bf16x8*)(smem + swz(OFF_ALPHA + d * 128 + c * 16)) = pk;
    }
    __syncthreads();   // bar3: alpha ready

    // ---- GEMM2: out[64][256] = alpha[64][64] @ Hs[64][256] ----
    f32x4 acc2[4][2];
#pragma unroll
    for (int mt = 0; mt < 4; ++mt) {
        acc2[mt][0] = (f32x4){0.f, 0.f, 0.f, 0.f};
        acc2[mt][1] = (f32x4){0.f, 0.f, 0.f, 0.f};
    }
#pragma unroll 1
    for (int ks = 0; ks < 2; ++ks) {
        int kk = ks * 32 + fh * 8;
        bf16x8 hbf0, hbf1;
        {
            int f0 = w * 32 + fl;
            int f1 = f0 + 16;
            hbf0 = *(const bf16x8*)(smem + swz(f0 * 128 + kk * 2));
            hbf1 = *(const bf16x8*)(smem + swz(f1 * 128 + kk * 2));
        }
#pragma unroll
        for (int mt = 0; mt < 4; ++mt) {
            bf16x8 aal = *(const bf16x8*)(smem + swz(OFF_ALPHA + (mt * 16 + fl) * 128 + kk * 2));
            acc2[mt][0] = __builtin_amdgcn_mfma_f32_16x16x32_bf16(aal, hbf0, acc2[mt][0], 0, 0, 0);
            acc2[mt][1] = __builtin_amdgcn_mfma_f32_16x16x32_bf16(aal, hbf1, acc2[mt][1], 0, 0, 0);
        }
    }

    // epilogue: + bias (loaded here, L2-hot), store fp32, mask r<63 / f<250
    float bv[2];
#pragma unroll
    for (int nti = 0; nti < 2; ++nti) {
        int f = w * 32 + nti * 16 + fl;
        bv[nti] = (f < F_DIM) ? bias[f] : 0.f;
    }
    float* ob = out + (size_t)b * (C_NODES * F_DIM);
#pragma unroll
    for (int mt = 0; mt < 4; ++mt) {
#pragma unroll
        for (int i = 0; i < 4; ++i) {
            int r = mt * 16 + fh * 4 + i;
            if (r < C_NODES) {
#pragma unroll
                for (int nti = 0; nti < 2; ++nti) {
                    int f = w * 32 + nti * 16 + fl;
                    if (f < F_DIM) ob[r * F_DIM + f] = acc2[mt][nti][i] + bv[nti];
                }
            }
        }
    }
}

extern "C" void kernel_launch(void* const* d_in, const int* in_sizes, int n_in,
                              void* d_out, int out_size, void* d_ws, size_t ws_size,
                              hipStream_t stream) {
    const float* x       = (const float*)d_in[0];
    const float* W       = (const float*)d_in[1];
    const float* att_src = (const float*)d_in[2];
    const float* att_dst = (const float*)d_in[3];
    const float* bias    = (const float*)d_in[4];
    float* out = (float*)d_out;
    bf16* Wp = (bf16*)d_ws;   // 65536 bf16 = 128 KB packed W (+score cols)

    gat_prep<<<256, 256, 0, stream>>>(W, att_src, att_dst, Wp);
    gat_main<<<4096, 512, 0, stream>>>(x, Wp, bias, out);
}